// Round 7
// baseline (128.146 us; speedup 1.0000x reference)
//
#include <hip/hip_runtime.h>

typedef _Float16 half_t;
typedef _Float16 hx8 __attribute__((ext_vector_type(8)));
typedef _Float16 hx4 __attribute__((ext_vector_type(4)));
typedef float fx4 __attribute__((ext_vector_type(4)));
typedef float fx2 __attribute__((ext_vector_type(2)));

#define LOG2E 1.44269504088896f
#define TAU 0.1f
#define NSPLIT 8

// Packed f32 VOP3P helpers (compiler never auto-emits these; operands are
// MFMA-quad subregister pairs so no packing movs should be generated).
__device__ __forceinline__ fx2 pk_mul(fx2 a, fx2 b) {
  fx2 d; asm("v_pk_mul_f32 %0, %1, %2" : "=v"(d) : "v"(a), "v"(b)); return d;
}
__device__ __forceinline__ fx2 pk_fma(fx2 a, fx2 b, fx2 c) {
  fx2 d; asm("v_pk_fma_f32 %0, %1, %2, %3" : "=v"(d) : "v"(a), "v"(b), "v"(c)); return d;
}
__device__ __forceinline__ fx2 pk_add(fx2 a, fx2 b) {
  fx2 d; asm("v_pk_add_f32 %0, %1, %2" : "=v"(d) : "v"(a), "v"(b)); return d;
}

// ---------------- Kernel 0: pack W1/W2 into fp16 A-fragment order ----------
// (unchanged — verified)
__global__ __launch_bounds__(256) void wpack_kernel(
    const float* __restrict__ W1, const float* __restrict__ W2,
    half_t* __restrict__ Wh1, half_t* __restrict__ Wh2)
{
  const int job = blockIdx.x*256 + threadIdx.x;   // 0..4095
  const int lane = job & 63;
  const int frag = (job >> 6) & 31;               // mt*4 + ks
  const int mat  = job >> 11;
  const int mt = frag >> 2, ks = frag & 3;
  const int q = lane >> 4, c = lane & 15;
  const float* W = mat ? W2 : W1;
  half_t* Wh = mat ? Wh2 : Wh1;
  hx8 v;
#pragma unroll
  for (int j=0;j<8;++j)
    v[j] = (half_t)W[(size_t)(ks*32 + q*8 + j)*128 + mt*16 + c];
  *(hx8*)(Wh + ((size_t)frag*64 + lane)*8) = v;
}

// ---------------- Kernel 1: fused ztrans + MLP (packed W frags) ------------
// (unchanged from round 6 — verified)
__global__ __launch_bounds__(256) void mlpz_kernel(
    const float* __restrict__ Z, const half_t* __restrict__ Wh1,
    const float* __restrict__ b1, const half_t* __restrict__ Wh2,
    const float* __restrict__ b2, half_t* __restrict__ T,
    half_t* __restrict__ Zth)
{
  __shared__ float Ztile[16*132];       // 8.45 KB
  __shared__ half_t Hs[16*136];         // 4.35 KB
  const int tid = threadIdx.x;
  const int w = tid >> 6, lane = tid & 63;
  const int q = lane >> 4, c = lane & 15;
  const int rb = blockIdx.x*16;

#pragma unroll
  for (int i=0;i<2;++i) {
    int fid = i*256 + tid;
    int r = fid >> 5, c4 = (fid & 31)*4;
    *(fx4*)(&Ztile[r*132 + c4]) = *(const fx4*)(Z + (size_t)(rb + r)*128 + c4);
  }
  __syncthreads();

  {
    const int d = tid >> 1, h = tid & 1;  // paired: 2 threads per d-row
    hx8 hv;
#pragma unroll
    for (int u=0;u<8;++u) hv[u] = (half_t)Ztile[(h*8 + u)*132 + d];
    *(hx8*)(Zth + (size_t)d*8192 + rb + h*8) = hv;
  }

  hx8 zb[4];
#pragma unroll
  for (int ks=0;ks<4;++ks) {
    fx4 a = *(const fx4*)(&Ztile[c*132 + ks*32 + q*8]);
    fx4 b = *(const fx4*)(&Ztile[c*132 + ks*32 + q*8 + 4]);
#pragma unroll
    for (int u=0;u<4;++u) { zb[ks][u] = (half_t)a[u]; zb[ks][4+u] = (half_t)b[u]; }
  }

  // ---- layer 1: wave w owns mt = 2w, 2w+1 ----
#pragma unroll
  for (int m2=0;m2<2;++m2) {
    const int mt = w*2 + m2;
    fx4 acc = (fx4){0.f,0.f,0.f,0.f};
#pragma unroll
    for (int ks=0;ks<4;++ks) {
      hx8 aw = *(const hx8*)(Wh1 + ((size_t)(mt*4 + ks)*64 + lane)*8);
      acc = __builtin_amdgcn_mfma_f32_16x16x32_f16(aw, zb[ks], acc, 0,0,0);
    }
    fx4 bias = *(const fx4*)(b1 + mt*16 + 4*q);
    hx4 hv;
#pragma unroll
    for (int i=0;i<4;++i) {
      float h = acc[i] + bias[i];
      hv[i] = (half_t)(h > 0.f ? h : 0.f);
    }
    *(hx4*)(&Hs[c*136 + mt*16 + 4*q]) = hv;
  }
  __syncthreads();

  // ---- layer 2 ----
  hx8 hb[4];
#pragma unroll
  for (int ks=0;ks<4;++ks) hb[ks] = *(const hx8*)(&Hs[c*136 + ks*32 + q*8]);
#pragma unroll
  for (int m2=0;m2<2;++m2) {
    const int mt = w*2 + m2;
    fx4 acc = (fx4){0.f,0.f,0.f,0.f};
#pragma unroll
    for (int ks=0;ks<4;++ks) {
      hx8 aw = *(const hx8*)(Wh2 + ((size_t)(mt*4 + ks)*64 + lane)*8);
      acc = __builtin_amdgcn_mfma_f32_16x16x32_f16(aw, hb[ks], acc, 0,0,0);
    }
    fx4 bias = *(const fx4*)(b2 + mt*16 + 4*q);
    hx4 tv;
#pragma unroll
    for (int i=0;i<4;++i) tv[i] = (half_t)(acc[i] + bias[i]);
    *(hx4*)(T + (size_t)(rb + c)*128 + mt*16 + 4*q) = tv;
  }
}

// ---------------- Kernel 2: flash attention partials (R6 + pk-f32 softmax) -
// R6 proven structure (55.6us: 64-key tiles, nt=2, grid 512, deferred l-sum,
// v_max3 tree). Round-7 change ONLY: softmax arithmetic in packed f32
// (v_pk_mul/fma/add_f32) — oacc rescale 64->32, p-fma 32->16, rs-add
// 32->16 instrs/iter. R6 counters: VALUBusy 34.6 > MfmaUtil 24.2 and the
// instruction arithmetic (460 VALU-cyc vs 307 MFMA-cyc/iter) matches —
// VALU pipe is the pacer; pk ops cut its issue count ~25%.
// Lessons ledger: (1) per-iter softmax aux dominates at small tiles — keep
// >=64-key tiles (R2); (2) occupancy bought by shrinking per-wave work is
// a LOSS (R3); (3) ALL MFMA operands in lgkmcnt domain (R1); (4) T13
// defer-max HURT (R4); (5) deferred l-sum WIN (R6: -2.8us); (6) P^T rows
// 128B with sw=(c&7)*8; (7) NEVER __launch_bounds__(256,3+).
__global__ __launch_bounds__(256,2) void flash_kernel(
    const half_t* __restrict__ T, const half_t* __restrict__ Zt,
    half_t* __restrict__ Pacc, float* __restrict__ Pm, float* __restrict__ Pl)
{
  __shared__ half_t Tbuf[2][16*512];    // 32 KB
  __shared__ half_t Zbuf[2][16*512];    // 32 KB
  const int tid = threadIdx.x;
  const int w = tid >> 6, lane = tid & 63;
  const int q = lane >> 4, c = lane & 15;
  const int bx = blockIdx.x;
  const int qb = bx >> 3, kh = bx & 7;
  const int wrow = qb*128 + w*32;
  const int sw = (c & 7) * 8;

  hx8 bq[2][4];
#pragma unroll
  for (int nt=0;nt<2;++nt)
#pragma unroll
    for (int ks=0;ks<4;++ks)
      bq[nt][ks] = *(const hx8*)(T + (size_t)(wrow + nt*16 + c)*128 + ks*32 + q*8);

  fx4 oacc[8][2];
#pragma unroll
  for (int mtd=0;mtd<8;++mtd)
#pragma unroll
    for (int nt=0;nt<2;++nt) oacc[mtd][nt] = (fx4){0.f,0.f,0.f,0.f};
  float m_run[2] = {-1e30f,-1e30f};
  float l_run[2] = {0.f,0.f};          // per-lane PARTIAL sums (reduced at end)

  const int kbase = kh*1024;

  auto issue_loads = [&](int kt0, int b) {
    if (w < 2) {
#pragma unroll
      for (int i=0;i<8;++i) {
        int f = w*8 + i, mt = f >> 2, ks = f & 3;
        const half_t* gp = T + (size_t)(kt0 + mt*16 + c)*128 + ks*32 + q*8;
        half_t* lp = &Tbuf[b][f*512 + lane*8];
        __builtin_amdgcn_global_load_lds(
            (const __attribute__((address_space(1))) void*)gp,
            (__attribute__((address_space(3))) void*)lp, 16, 0, 0);
      }
    } else {
#pragma unroll
      for (int i=0;i<8;++i) {
        int f2 = (w-2)*8 + i, mtd = f2 >> 1, ks2 = f2 & 1;
        const half_t* gp = Zt + (size_t)(mtd*16 + c)*8192 + kt0 + ks2*32 + q*8;
        half_t* lp = &Zbuf[b][f2*512 + lane*8];
        __builtin_amdgcn_global_load_lds(
            (const __attribute__((address_space(1))) void*)gp,
            (__attribute__((address_space(3))) void*)lp, 16, 0, 0);
      }
    }
  };

  issue_loads(kbase, 0);

  for (int t=0;t<16;++t) {
    const int cur = t & 1;
    __syncthreads();                    // drains DMA fills of cur + publishes
    half_t* Tcur = Tbuf[cur];
    half_t* Zcur = Zbuf[cur];
    half_t* Psw  = &Tbuf[cur][w*2048];

    // ---- scores ----
    fx4 sacc[4][2];
#pragma unroll
    for (int mt=0;mt<4;++mt)
#pragma unroll
      for (int nt=0;nt<2;++nt) sacc[mt][nt] = (fx4){0.f,0.f,0.f,0.f};
#pragma unroll
    for (int ks=0;ks<4;++ks)
#pragma unroll
      for (int mt=0;mt<4;++mt) {
        hx8 ak = *(const hx8*)(&Tcur[(mt*4+ks)*512 + lane*8]);
        sacc[mt][0] = __builtin_amdgcn_mfma_f32_16x16x32_f16(ak, bq[0][ks], sacc[mt][0], 0,0,0);
        sacc[mt][1] = __builtin_amdgcn_mfma_f32_16x16x32_f16(ak, bq[1][ks], sacc[mt][1], 0,0,0);
      }

    // ---- online softmax (pk-f32; per-lane partial l; only MAX shfl'd) ----
    hx4 pk[2][4];
#pragma unroll
    for (int nt=0;nt<2;++nt) {
      // max tree nested in triples -> v_max3
      float a0 = fmaxf(fmaxf(sacc[0][nt][0], sacc[0][nt][1]), sacc[0][nt][2]);
      float a1 = fmaxf(fmaxf(sacc[0][nt][3], sacc[1][nt][0]), sacc[1][nt][1]);
      float a2 = fmaxf(fmaxf(sacc[1][nt][2], sacc[1][nt][3]), sacc[2][nt][0]);
      float a3 = fmaxf(fmaxf(sacc[2][nt][1], sacc[2][nt][2]), sacc[2][nt][3]);
      float a4 = fmaxf(fmaxf(sacc[3][nt][0], sacc[3][nt][1]), sacc[3][nt][2]);
      float mx = fmaxf(fmaxf(fmaxf(a0, a1), fmaxf(a2, a3)),
                       fmaxf(a4, sacc[3][nt][3]));
      mx = fmaxf(mx, __shfl_xor(mx, 16, 64));
      mx = fmaxf(mx, __shfl_xor(mx, 32, 64));
      float mnew = fmaxf(m_run[nt], mx);
      float alpha = __builtin_amdgcn_exp2f((m_run[nt]-mnew)*LOG2E);
      m_run[nt] = mnew;
      const float nb = mnew*LOG2E;
      const fx2 log2e2 = (fx2){LOG2E, LOG2E};
      const fx2 nbn2   = (fx2){-nb, -nb};
      fx2 rs2 = (fx2){0.f, 0.f};
#pragma unroll
      for (int mt=0;mt<4;++mt) {
#pragma unroll
        for (int h2=0;h2<2;++h2) {
          fx2 s2 = (fx2){ sacc[mt][nt][2*h2], sacc[mt][nt][2*h2+1] };
          fx2 e2 = pk_fma(s2, log2e2, nbn2);
          float p0 = __builtin_amdgcn_exp2f(e2[0]);
          float p1 = __builtin_amdgcn_exp2f(e2[1]);
          rs2 = pk_add(rs2, (fx2){p0, p1});
          pk[nt][mt][2*h2]   = (half_t)p0;
          pk[nt][mt][2*h2+1] = (half_t)p1;
        }
      }
      l_run[nt] = l_run[nt]*alpha + (rs2[0] + rs2[1]);
      const fx2 al2 = (fx2){alpha, alpha};
#pragma unroll
      for (int mtd=0;mtd<8;++mtd) {
        fx2 lo = (fx2){oacc[mtd][nt][0], oacc[mtd][nt][1]};
        fx2 hi = (fx2){oacc[mtd][nt][2], oacc[mtd][nt][3]};
        lo = pk_mul(lo, al2);
        hi = pk_mul(hi, al2);
        oacc[mtd][nt][0] = lo[0]; oacc[mtd][nt][1] = lo[1];
        oacc[mtd][nt][2] = hi[0]; oacc[mtd][nt][3] = hi[1];
      }
    }

    __syncthreads();                    // all scores reads of Tcur done
    if (t < 15) issue_loads(kbase + (t+1)*64, cur ^ 1);

    // P^T into dead Tcur region, per-wave, xor-swizzled
#pragma unroll
    for (int nt=0;nt<2;++nt)
#pragma unroll
      for (int mt=0;mt<4;++mt)
        *(hx4*)(&Psw[(nt*16 + c)*64 + ((mt*16 + 4*q) ^ sw)]) = pk[nt][mt];

    // ---- PV ----
#pragma unroll
    for (int ks2=0;ks2<2;++ks2) {
      hx8 bp0 = *(const hx8*)(&Psw[(c     )*64 + ((ks2*32 + q*8) ^ sw)]);
      hx8 bp1 = *(const hx8*)(&Psw[(16 + c)*64 + ((ks2*32 + q*8) ^ sw)]);
#pragma unroll
      for (int mtd=0;mtd<8;++mtd) {
        hx8 az = *(const hx8*)(&Zcur[(mtd*2+ks2)*512 + lane*8]);
        oacc[mtd][0] = __builtin_amdgcn_mfma_f32_16x16x32_f16(az, bp0, oacc[mtd][0], 0,0,0);
        oacc[mtd][1] = __builtin_amdgcn_mfma_f32_16x16x32_f16(az, bp1, oacc[mtd][1], 0,0,0);
      }
    }
  }

  // epilogue: reduce the deferred l partials across the 4 lanes per q-row
#pragma unroll
  for (int nt=0;nt<2;++nt) {
    float lf = l_run[nt];
    lf += __shfl_xor(lf, 16, 64);
    lf += __shfl_xor(lf, 32, 64);
    float inv = 1.0f / lf;
    const size_t rowg = (size_t)(bx*128 + w*32 + nt*16 + c);
#pragma unroll
    for (int mtd=0;mtd<8;++mtd) {
      hx4 ov;
#pragma unroll
      for (int i=0;i<4;++i) ov[i] = (half_t)(oacc[mtd][nt][i]*inv);
      *(hx4*)(Pacc + rowg*128 + mtd*16 + 4*q) = ov;
    }
    if (q == 0) {
      Pm[rowg] = m_run[nt];
      Pl[rowg] = lf;
    }
  }
}

// ---------------- Kernel 3: merge NSPLIT key-split partials ----------------
// (unchanged)
__global__ __launch_bounds__(256) void merge_kernel(
    const float* __restrict__ Z, const half_t* __restrict__ Pacc,
    const float* __restrict__ Pm, const float* __restrict__ Pl,
    float* __restrict__ out)
{
  const int th = blockIdx.x*256 + threadIdx.x;
  const int r = th >> 5, cg = th & 31;
  const int qb = r >> 7, rr = r & 127;
  float mk[NSPLIT], lk[NSPLIT];
  float M = -1e30f;
#pragma unroll
  for (int k=0;k<NSPLIT;++k) {
    int p = qb*NSPLIT + k;
    mk[k] = Pm[p*128 + rr];
    lk[k] = Pl[p*128 + rr];
    M = fmaxf(M, mk[k]);
  }
  float L = 0.f, wk[NSPLIT];
#pragma unroll
  for (int k=0;k<NSPLIT;++k) { wk[k] = lk[k]*__builtin_amdgcn_exp2f((mk[k]-M)*LOG2E); L += wk[k]; }
  float o0=0.f,o1=0.f,o2=0.f,o3=0.f;
#pragma unroll
  for (int k=0;k<NSPLIT;++k) {
    int p = qb*NSPLIT + k;
    hx4 v = *(const hx4*)(Pacc + ((size_t)p*128 + rr)*128 + cg*4);
    o0 += wk[k]*(float)v[0]; o1 += wk[k]*(float)v[1];
    o2 += wk[k]*(float)v[2]; o3 += wk[k]*(float)v[3];
  }
  float invL = 1.0f / L;
  fx4 zv = *(const fx4*)(Z + (size_t)r*128 + cg*4);
  fx4 res;
  res[0] = (1.f-TAU)*zv[0] + TAU*o0*invL;
  res[1] = (1.f-TAU)*zv[1] + TAU*o1*invL;
  res[2] = (1.f-TAU)*zv[2] + TAU*o2*invL;
  res[3] = (1.f-TAU)*zv[3] + TAU*o3*invL;
  *(fx4*)(out + (size_t)r*128 + cg*4) = res;
}

extern "C" void kernel_launch(void* const* d_in, const int* in_sizes, int n_in,
                              void* d_out, int out_size, void* d_ws, size_t ws_size,
                              hipStream_t stream) {
  const float* Z  = (const float*)d_in[0];
  const float* W1 = (const float*)d_in[1];
  const float* b1 = (const float*)d_in[2];
  const float* W2 = (const float*)d_in[3];
  const float* b2 = (const float*)d_in[4];
  float* out = (float*)d_out;

  char* ws = (char*)d_ws;
  const size_t NBLK = 64 * NSPLIT;                                // 512
  half_t* Thi  = (half_t*)(ws);                                   // 2 MB
  half_t* Zth  = (half_t*)(ws + (size_t)2*1024*1024);             // 2 MB
  half_t* Pacc = (half_t*)(ws + (size_t)4*1024*1024);             // 16 MB
  float*  Pm   = (float*)(ws + (size_t)4*1024*1024 + NBLK*128*128*2);
  float*  Pl   = Pm + NBLK*128;
  half_t* Wh1  = (half_t*)(ws + (size_t)20*1024*1024 + 512*1024); // 32 KB
  half_t* Wh2  = Wh1 + 32*64*8;                                   // 32 KB

  hipLaunchKernelGGL(wpack_kernel, dim3(16),   dim3(256), 0, stream, W1, W2, Wh1, Wh2);
  hipLaunchKernelGGL(mlpz_kernel,  dim3(512),  dim3(256), 0, stream, Z, Wh1, b1, Wh2, b2, Thi, Zth);
  hipLaunchKernelGGL(flash_kernel, dim3(NBLK), dim3(256), 0, stream, Thi, Zth, Pacc, Pm, Pl);
  hipLaunchKernelGGL(merge_kernel, dim3(1024), dim3(256), 0, stream, Z, Pacc, Pm, Pl, out);
}

// Round 8
// 122.515 us; speedup vs baseline: 1.0460x; 1.0460x over previous
//
#include <hip/hip_runtime.h>

typedef _Float16 half_t;
typedef _Float16 hx8 __attribute__((ext_vector_type(8)));
typedef _Float16 hx4 __attribute__((ext_vector_type(4)));
typedef float fx4 __attribute__((ext_vector_type(4)));

#define LOG2E 1.44269504088896f
#define TAU 0.1f
#define NSPLIT 8

// ---------------- Kernel 0: pack W1/W2 into fp16 A-fragment order ----------
// (unchanged — verified)
__global__ __launch_bounds__(256) void wpack_kernel(
    const float* __restrict__ W1, const float* __restrict__ W2,
    half_t* __restrict__ Wh1, half_t* __restrict__ Wh2)
{
  const int job = blockIdx.x*256 + threadIdx.x;   // 0..4095
  const int lane = job & 63;
  const int frag = (job >> 6) & 31;               // mt*4 + ks
  const int mat  = job >> 11;
  const int mt = frag >> 2, ks = frag & 3;
  const int q = lane >> 4, c = lane & 15;
  const float* W = mat ? W2 : W1;
  half_t* Wh = mat ? Wh2 : Wh1;
  hx8 v;
#pragma unroll
  for (int j=0;j<8;++j)
    v[j] = (half_t)W[(size_t)(ks*32 + q*8 + j)*128 + mt*16 + c];
  *(hx8*)(Wh + ((size_t)frag*64 + lane)*8) = v;
}

// ---------------- Kernel 1: fused ztrans + MLP (packed W frags) ------------
// (unchanged from round 6 — verified)
__global__ __launch_bounds__(256) void mlpz_kernel(
    const float* __restrict__ Z, const half_t* __restrict__ Wh1,
    const float* __restrict__ b1, const half_t* __restrict__ Wh2,
    const float* __restrict__ b2, half_t* __restrict__ T,
    half_t* __restrict__ Zth)
{
  __shared__ float Ztile[16*132];       // 8.45 KB
  __shared__ half_t Hs[16*136];         // 4.35 KB
  const int tid = threadIdx.x;
  const int w = tid >> 6, lane = tid & 63;
  const int q = lane >> 4, c = lane & 15;
  const int rb = blockIdx.x*16;

#pragma unroll
  for (int i=0;i<2;++i) {
    int fid = i*256 + tid;
    int r = fid >> 5, c4 = (fid & 31)*4;
    *(fx4*)(&Ztile[r*132 + c4]) = *(const fx4*)(Z + (size_t)(rb + r)*128 + c4);
  }
  __syncthreads();

  {
    const int d = tid >> 1, h = tid & 1;  // paired: 2 threads per d-row
    hx8 hv;
#pragma unroll
    for (int u=0;u<8;++u) hv[u] = (half_t)Ztile[(h*8 + u)*132 + d];
    *(hx8*)(Zth + (size_t)d*8192 + rb + h*8) = hv;
  }

  hx8 zb[4];
#pragma unroll
  for (int ks=0;ks<4;++ks) {
    fx4 a = *(const fx4*)(&Ztile[c*132 + ks*32 + q*8]);
    fx4 b = *(const fx4*)(&Ztile[c*132 + ks*32 + q*8 + 4]);
#pragma unroll
    for (int u=0;u<4;++u) { zb[ks][u] = (half_t)a[u]; zb[ks][4+u] = (half_t)b[u]; }
  }

  // ---- layer 1: wave w owns mt = 2w, 2w+1 ----
#pragma unroll
  for (int m2=0;m2<2;++m2) {
    const int mt = w*2 + m2;
    fx4 acc = (fx4){0.f,0.f,0.f,0.f};
#pragma unroll
    for (int ks=0;ks<4;++ks) {
      hx8 aw = *(const hx8*)(Wh1 + ((size_t)(mt*4 + ks)*64 + lane)*8);
      acc = __builtin_amdgcn_mfma_f32_16x16x32_f16(aw, zb[ks], acc, 0,0,0);
    }
    fx4 bias = *(const fx4*)(b1 + mt*16 + 4*q);
    hx4 hv;
#pragma unroll
    for (int i=0;i<4;++i) {
      float h = acc[i] + bias[i];
      hv[i] = (half_t)(h > 0.f ? h : 0.f);
    }
    *(hx4*)(&Hs[c*136 + mt*16 + 4*q]) = hv;
  }
  __syncthreads();

  // ---- layer 2 ----
  hx8 hb[4];
#pragma unroll
  for (int ks=0;ks<4;++ks) hb[ks] = *(const hx8*)(&Hs[c*136 + ks*32 + q*8]);
#pragma unroll
  for (int m2=0;m2<2;++m2) {
    const int mt = w*2 + m2;
    fx4 acc = (fx4){0.f,0.f,0.f,0.f};
#pragma unroll
    for (int ks=0;ks<4;++ks) {
      hx8 aw = *(const hx8*)(Wh2 + ((size_t)(mt*4 + ks)*64 + lane)*8);
      acc = __builtin_amdgcn_mfma_f32_16x16x32_f16(aw, hb[ks], acc, 0,0,0);
    }
    fx4 bias = *(const fx4*)(b2 + mt*16 + 4*q);
    hx4 tv;
#pragma unroll
    for (int i=0;i<4;++i) tv[i] = (half_t)(acc[i] + bias[i]);
    *(hx4*)(T + (size_t)(rb + c)*128 + mt*16 + 4*q) = tv;
  }
}

// ---------------- Kernel 2: flash attention partials (R6 + 1-barrier) ------
// R6 proven core (55.6us: 64-key tiles, nt=2, grid 512, deferred l-sum,
// v_max3 tree, scalar softmax). Round-8 changes ONLY:
//  (a) P^T gets a DEDICATED per-wave LDS region (16 KB; P is wave-private
//      — written and read only by its own wave) instead of aliasing the
//      scores-dead Tcur region. That alias was the ONLY reason for the
//      second barrier (inter-wave write-vs-scores-read race).
//  (b) sync_b DELETED -> 1 barrier/iter; waves decouple for the whole
//      iteration body (PV of wave w overlaps softmax of wave w').
//  (c) DMA issue hoisted to right after sync_a: cur^1 is provably dead
//      there (barrier retired all t-1 reads) -> prefetch distance = full
//      iteration. vmcnt queue still exclusively DMA (R1 lesson).
// LDS 64->80 KB: 2x80 = 160 KB = exactly 2 blocks/CU (occupancy unchanged
// by design — this round attacks rendezvous count, not occupancy).
// Lessons ledger: (1) per-iter softmax aux dominates at small tiles — keep
// >=64-key tiles (R2); (2) occupancy bought by shrinking per-wave work is
// a LOSS (R3); (3) ALL MFMA operands in lgkmcnt domain (R1); (4) T13
// defer-max HURT (R4); (5) deferred l-sum WIN (R6: -2.8us); (6) hand-packed
// v_pk_f32 on live accumulators -> 128-VGPR cliff + scratch spills, +4.6us
// (R7: FETCH/WRITE rose ~3.4MB) — keep scalar softmax, VGPR<=~120;
// (7) P^T rows 128B with sw=(c&7)*8; (8) NEVER __launch_bounds__(256,3+).
__global__ __launch_bounds__(256,2) void flash_kernel(
    const half_t* __restrict__ T, const half_t* __restrict__ Zt,
    half_t* __restrict__ Pacc, float* __restrict__ Pm, float* __restrict__ Pl)
{
  __shared__ half_t Tbuf[2][16*512];    // 32 KB
  __shared__ half_t Zbuf[2][16*512];    // 32 KB
  __shared__ half_t Pbuf[4][32*64];     // 16 KB — per-wave private P^T
  const int tid = threadIdx.x;
  const int w = tid >> 6, lane = tid & 63;
  const int q = lane >> 4, c = lane & 15;
  const int bx = blockIdx.x;
  const int qb = bx >> 3, kh = bx & 7;
  const int wrow = qb*128 + w*32;
  const int sw = (c & 7) * 8;

  hx8 bq[2][4];
#pragma unroll
  for (int nt=0;nt<2;++nt)
#pragma unroll
    for (int ks=0;ks<4;++ks)
      bq[nt][ks] = *(const hx8*)(T + (size_t)(wrow + nt*16 + c)*128 + ks*32 + q*8);

  fx4 oacc[8][2];
#pragma unroll
  for (int mtd=0;mtd<8;++mtd)
#pragma unroll
    for (int nt=0;nt<2;++nt) oacc[mtd][nt] = (fx4){0.f,0.f,0.f,0.f};
  float m_run[2] = {-1e30f,-1e30f};
  float l_run[2] = {0.f,0.f};          // per-lane PARTIAL sums (reduced at end)

  const int kbase = kh*1024;
  half_t* Psw = &Pbuf[w][0];           // wave-private 32x64-half P^T

  auto issue_loads = [&](int kt0, int b) {
    if (w < 2) {
#pragma unroll
      for (int i=0;i<8;++i) {
        int f = w*8 + i, mt = f >> 2, ks = f & 3;
        const half_t* gp = T + (size_t)(kt0 + mt*16 + c)*128 + ks*32 + q*8;
        half_t* lp = &Tbuf[b][f*512 + lane*8];
        __builtin_amdgcn_global_load_lds(
            (const __attribute__((address_space(1))) void*)gp,
            (__attribute__((address_space(3))) void*)lp, 16, 0, 0);
      }
    } else {
#pragma unroll
      for (int i=0;i<8;++i) {
        int f2 = (w-2)*8 + i, mtd = f2 >> 1, ks2 = f2 & 1;
        const half_t* gp = Zt + (size_t)(mtd*16 + c)*8192 + kt0 + ks2*32 + q*8;
        half_t* lp = &Zbuf[b][f2*512 + lane*8];
        __builtin_amdgcn_global_load_lds(
            (const __attribute__((address_space(1))) void*)gp,
            (__attribute__((address_space(3))) void*)lp, 16, 0, 0);
      }
    }
  };

  issue_loads(kbase, 0);

  for (int t=0;t<16;++t) {
    const int cur = t & 1;
    __syncthreads();                    // THE barrier: drains own DMA (vmcnt)
                                        // + publishes both buffers of iter t
    half_t* Tcur = Tbuf[cur];
    half_t* Zcur = Zbuf[cur];

    // prefetch t+1 NOW: cur^1 is dead (barrier retired all t-1 reads);
    // fills have the whole iteration to land before the next barrier.
    if (t < 15) issue_loads(kbase + (t+1)*64, cur ^ 1);

    // ---- scores ----
    fx4 sacc[4][2];
#pragma unroll
    for (int mt=0;mt<4;++mt)
#pragma unroll
      for (int nt=0;nt<2;++nt) sacc[mt][nt] = (fx4){0.f,0.f,0.f,0.f};
#pragma unroll
    for (int ks=0;ks<4;++ks)
#pragma unroll
      for (int mt=0;mt<4;++mt) {
        hx8 ak = *(const hx8*)(&Tcur[(mt*4+ks)*512 + lane*8]);
        sacc[mt][0] = __builtin_amdgcn_mfma_f32_16x16x32_f16(ak, bq[0][ks], sacc[mt][0], 0,0,0);
        sacc[mt][1] = __builtin_amdgcn_mfma_f32_16x16x32_f16(ak, bq[1][ks], sacc[mt][1], 0,0,0);
      }

    // ---- online softmax (per-lane partial l; only the MAX is shfl'd) ----
    hx4 pk[2][4];
#pragma unroll
    for (int nt=0;nt<2;++nt) {
      float a0 = fmaxf(fmaxf(sacc[0][nt][0], sacc[0][nt][1]), sacc[0][nt][2]);
      float a1 = fmaxf(fmaxf(sacc[0][nt][3], sacc[1][nt][0]), sacc[1][nt][1]);
      float a2 = fmaxf(fmaxf(sacc[1][nt][2], sacc[1][nt][3]), sacc[2][nt][0]);
      float a3 = fmaxf(fmaxf(sacc[2][nt][1], sacc[2][nt][2]), sacc[2][nt][3]);
      float a4 = fmaxf(fmaxf(sacc[3][nt][0], sacc[3][nt][1]), sacc[3][nt][2]);
      float mx = fmaxf(fmaxf(fmaxf(a0, a1), fmaxf(a2, a3)),
                       fmaxf(a4, sacc[3][nt][3]));
      mx = fmaxf(mx, __shfl_xor(mx, 16, 64));
      mx = fmaxf(mx, __shfl_xor(mx, 32, 64));
      float mnew = fmaxf(m_run[nt], mx);
      float alpha = __builtin_amdgcn_exp2f((m_run[nt]-mnew)*LOG2E);
      m_run[nt] = mnew;
      float nb = mnew*LOG2E;
      float rs = 0.f;
#pragma unroll
      for (int mt=0;mt<4;++mt) {
#pragma unroll
        for (int i=0;i<4;++i) {
          float p = __builtin_amdgcn_exp2f(sacc[mt][nt][i]*LOG2E - nb);
          rs += p;
          pk[nt][mt][i] = (half_t)p;
        }
      }
      l_run[nt] = l_run[nt]*alpha + rs;   // per-lane partial (no shfl here)
#pragma unroll
      for (int mtd=0;mtd<8;++mtd)
#pragma unroll
        for (int i=0;i<4;++i) oacc[mtd][nt][i] *= alpha;
    }

    // P^T into wave-private region (no inter-wave race -> NO barrier)
#pragma unroll
    for (int nt=0;nt<2;++nt)
#pragma unroll
      for (int mt=0;mt<4;++mt)
        *(hx4*)(&Psw[(nt*16 + c)*64 + ((mt*16 + 4*q) ^ sw)]) = pk[nt][mt];

    // ---- PV ----
#pragma unroll
    for (int ks2=0;ks2<2;++ks2) {
      hx8 bp0 = *(const hx8*)(&Psw[(c     )*64 + ((ks2*32 + q*8) ^ sw)]);
      hx8 bp1 = *(const hx8*)(&Psw[(16 + c)*64 + ((ks2*32 + q*8) ^ sw)]);
#pragma unroll
      for (int mtd=0;mtd<8;++mtd) {
        hx8 az = *(const hx8*)(&Zcur[(mtd*2+ks2)*512 + lane*8]);
        oacc[mtd][0] = __builtin_amdgcn_mfma_f32_16x16x32_f16(az, bp0, oacc[mtd][0], 0,0,0);
        oacc[mtd][1] = __builtin_amdgcn_mfma_f32_16x16x32_f16(az, bp1, oacc[mtd][1], 0,0,0);
      }
    }
  }

  // epilogue: reduce the deferred l partials across the 4 lanes per q-row
#pragma unroll
  for (int nt=0;nt<2;++nt) {
    float lf = l_run[nt];
    lf += __shfl_xor(lf, 16, 64);
    lf += __shfl_xor(lf, 32, 64);
    float inv = 1.0f / lf;
    const size_t rowg = (size_t)(bx*128 + w*32 + nt*16 + c);
#pragma unroll
    for (int mtd=0;mtd<8;++mtd) {
      hx4 ov;
#pragma unroll
      for (int i=0;i<4;++i) ov[i] = (half_t)(oacc[mtd][nt][i]*inv);
      *(hx4*)(Pacc + rowg*128 + mtd*16 + 4*q) = ov;
    }
    if (q == 0) {
      Pm[rowg] = m_run[nt];
      Pl[rowg] = lf;
    }
  }
}

// ---------------- Kernel 3: merge NSPLIT key-split partials ----------------
// (unchanged)
__global__ __launch_bounds__(256) void merge_kernel(
    const float* __restrict__ Z, const half_t* __restrict__ Pacc,
    const float* __restrict__ Pm, const float* __restrict__ Pl,
    float* __restrict__ out)
{
  const int th = blockIdx.x*256 + threadIdx.x;
  const int r = th >> 5, cg = th & 31;
  const int qb = r >> 7, rr = r & 127;
  float mk[NSPLIT], lk[NSPLIT];
  float M = -1e30f;
#pragma unroll
  for (int k=0;k<NSPLIT;++k) {
    int p = qb*NSPLIT + k;
    mk[k] = Pm[p*128 + rr];
    lk[k] = Pl[p*128 + rr];
    M = fmaxf(M, mk[k]);
  }
  float L = 0.f, wk[NSPLIT];
#pragma unroll
  for (int k=0;k<NSPLIT;++k) { wk[k] = lk[k]*__builtin_amdgcn_exp2f((mk[k]-M)*LOG2E); L += wk[k]; }
  float o0=0.f,o1=0.f,o2=0.f,o3=0.f;
#pragma unroll
  for (int k=0;k<NSPLIT;++k) {
    int p = qb*NSPLIT + k;
    hx4 v = *(const hx4*)(Pacc + ((size_t)p*128 + rr)*128 + cg*4);
    o0 += wk[k]*(float)v[0]; o1 += wk[k]*(float)v[1];
    o2 += wk[k]*(float)v[2]; o3 += wk[k]*(float)v[3];
  }
  float invL = 1.0f / L;
  fx4 zv = *(const fx4*)(Z + (size_t)r*128 + cg*4);
  fx4 res;
  res[0] = (1.f-TAU)*zv[0] + TAU*o0*invL;
  res[1] = (1.f-TAU)*zv[1] + TAU*o1*invL;
  res[2] = (1.f-TAU)*zv[2] + TAU*o2*invL;
  res[3] = (1.f-TAU)*zv[3] + TAU*o3*invL;
  *(fx4*)(out + (size_t)r*128 + cg*4) = res;
}

extern "C" void kernel_launch(void* const* d_in, const int* in_sizes, int n_in,
                              void* d_out, int out_size, void* d_ws, size_t ws_size,
                              hipStream_t stream) {
  const float* Z  = (const float*)d_in[0];
  const float* W1 = (const float*)d_in[1];
  const float* b1 = (const float*)d_in[2];
  const float* W2 = (const float*)d_in[3];
  const float* b2 = (const float*)d_in[4];
  float* out = (float*)d_out;

  char* ws = (char*)d_ws;
  const size_t NBLK = 64 * NSPLIT;                                // 512
  half_t* Thi  = (half_t*)(ws);                                   // 2 MB
  half_t* Zth  = (half_t*)(ws + (size_t)2*1024*1024);             // 2 MB
  half_t* Pacc = (half_t*)(ws + (size_t)4*1024*1024);             // 16 MB
  float*  Pm   = (float*)(ws + (size_t)4*1024*1024 + NBLK*128*128*2);
  float*  Pl   = Pm + NBLK*128;
  half_t* Wh1  = (half_t*)(ws + (size_t)20*1024*1024 + 512*1024); // 32 KB
  half_t* Wh2  = Wh1 + 32*64*8;                                   // 32 KB

  hipLaunchKernelGGL(wpack_kernel, dim3(16),   dim3(256), 0, stream, W1, W2, Wh1, Wh2);
  hipLaunchKernelGGL(mlpz_kernel,  dim3(512),  dim3(256), 0, stream, Z, Wh1, b1, Wh2, b2, Thi, Zth);
  hipLaunchKernelGGL(flash_kernel, dim3(NBLK), dim3(256), 0, stream, Thi, Zth, Pacc, Pm, Pl);
  hipLaunchKernelGGL(merge_kernel, dim3(1024), dim3(256), 0, stream, Z, Pacc, Pm, Pl, out);
}